// Round 1
// baseline (452.049 us; speedup 1.0000x reference)
//
#include <hip/hip_runtime.h>

#define NN 100000
#define SS 50000
#define KK 32
#define CC 128

// Kernel 1: P = leaky_relu(word_vec @ W^T + b)  -> write to BOTH ws (P) and out.
// Tile: 64 rows x 64 cols per block (blockIdx.y = col half), 4x4 per thread.
// LDS: sA[64][128] (32KB) + sB[128][64] (32KB, transposed W) = 64KB exact.
__global__ __launch_bounds__(256) void proj_kernel(
    const float* __restrict__ wv,
    const float* __restrict__ W,
    const float* __restrict__ bias,
    float* __restrict__ P,
    float* __restrict__ out)
{
    __shared__ float sA[64][128];
    __shared__ float sB[128][64];   // sB[k][ol] = W[og0+ol][k]

    const int t = threadIdx.x;
    const int row0 = blockIdx.x * 64;
    const int og0 = blockIdx.y * 64;

    // Stage sB (transpose W columns og0..og0+63). Scalar global reads (W is
    // 64KB, L2-resident for all blocks); LDS writes are contiguous b128.
    {
        const int ol4 = (t & 15) * 4;
        #pragma unroll
        for (int pass = 0; pass < 8; pass++) {
            const int k = (t >> 4) + pass * 16;
            float4 w;
            w.x = W[(size_t)(og0 + ol4 + 0) * CC + k];
            w.y = W[(size_t)(og0 + ol4 + 1) * CC + k];
            w.z = W[(size_t)(og0 + ol4 + 2) * CC + k];
            w.w = W[(size_t)(og0 + ol4 + 3) * CC + k];
            *(float4*)&sB[k][ol4] = w;
        }
    }
    // Stage sA: coalesced float4 global reads, contiguous b128 LDS writes.
    {
        const int k4 = (t & 31) * 4;
        #pragma unroll
        for (int pass = 0; pass < 8; pass++) {
            const int r = (t >> 5) + pass * 8;
            const int gr = row0 + r;
            float4 v = make_float4(0.f, 0.f, 0.f, 0.f);
            if (gr < NN) v = *(const float4*)(wv + (size_t)gr * CC + k4);
            *(float4*)&sA[r][k4] = v;
        }
    }
    __syncthreads();

    const int r0 = (t >> 4) * 4;   // 16 row-groups
    const int c0 = (t & 15) * 4;   // 16 col-groups
    float acc[4][4] = {};

    for (int k = 0; k < CC; k += 4) {
        const float4 B0 = *(const float4*)&sB[k + 0][c0];
        const float4 B1 = *(const float4*)&sB[k + 1][c0];
        const float4 B2 = *(const float4*)&sB[k + 2][c0];
        const float4 B3 = *(const float4*)&sB[k + 3][c0];
        #pragma unroll
        for (int i = 0; i < 4; i++) {
            const float4 Ai = *(const float4*)&sA[r0 + i][k];
            acc[i][0] += Ai.x * B0.x + Ai.y * B1.x + Ai.z * B2.x + Ai.w * B3.x;
            acc[i][1] += Ai.x * B0.y + Ai.y * B1.y + Ai.z * B2.y + Ai.w * B3.y;
            acc[i][2] += Ai.x * B0.z + Ai.y * B1.z + Ai.z * B2.z + Ai.w * B3.z;
            acc[i][3] += Ai.x * B0.w + Ai.y * B1.w + Ai.z * B2.w + Ai.w * B3.w;
        }
    }

    const float4 bv = *(const float4*)(bias + og0 + c0);
    #pragma unroll
    for (int i = 0; i < 4; i++) {
        const int gr = row0 + r0 + i;
        if (gr < NN) {
            float4 o;
            o.x = acc[i][0] + bv.x;
            o.y = acc[i][1] + bv.y;
            o.z = acc[i][2] + bv.z;
            o.w = acc[i][3] + bv.w;
            o.x = o.x > 0.f ? o.x : 0.2f * o.x;
            o.y = o.y > 0.f ? o.y : 0.2f * o.y;
            o.z = o.z > 0.f ? o.z : 0.2f * o.z;
            o.w = o.w > 0.f ? o.w : 0.2f * o.w;
            const size_t off = (size_t)gr * CC + og0 + c0;
            *(float4*)(P + off) = o;
            *(float4*)(out + off) = o;
        }
    }
}

// Kernel 2: one wave per s. Scores from raw word_vec, masked softmax over
// K=32, then agg = sum_k prob*P[neigh] written to out[src_idx[s]].
__global__ __launch_bounds__(256) void attn_kernel(
    const float* __restrict__ wv,
    const int* __restrict__ src_idx,
    const int* __restrict__ neighs,
    const int* __restrict__ mask,
    const float* __restrict__ P,
    float* __restrict__ out)
{
    const int gtid = blockIdx.x * blockDim.x + threadIdx.x;
    const int s = gtid >> 6;
    if (s >= SS) return;
    const int lane = threadIdx.x & 63;
    const int n = lane & 31;   // neighbor handled by this lane
    const int h = lane >> 5;   // channel half: [h*64, h*64+64)

    const int nb  = neighs[(size_t)s * KK + n];
    const int m   = mask[(size_t)s * KK + n];
    const int src = src_idx[s];

    const float4* q4 = (const float4*)(wv + (size_t)src * CC) + h * 16;
    const float4* k4 = (const float4*)(wv + (size_t)nb * CC) + h * 16;
    float acc = 0.f;
    #pragma unroll
    for (int i = 0; i < 16; i++) {
        const float4 a = q4[i];
        const float4 b = k4[i];
        acc += a.x * b.x + a.y * b.y + a.z * b.z + a.w * b.w;
    }
    acc += __shfl_xor(acc, 32);             // full 128-dot in both halves
    float score = (m == 1) ? acc * 5.0f : -1e6f;

    // softmax over the 32 neighbor scores (each half holds the full set)
    float mx = score;
    #pragma unroll
    for (int d = 1; d < 32; d <<= 1) mx = fmaxf(mx, __shfl_xor(mx, d));
    const float e = __expf(score - mx);
    float sum = e;
    #pragma unroll
    for (int d = 1; d < 32; d <<= 1) sum += __shfl_xor(sum, d);
    const float p = e / sum;

    // aggregation: lane owns output cols [2*lane, 2*lane+1]
    float2 a2 = make_float2(0.f, 0.f);
    #pragma unroll 8
    for (int j = 0; j < 32; j++) {
        const int   idx = __shfl(nb, j);
        const float pj  = __shfl(p, j);
        const float2 v = *((const float2*)(P + (size_t)idx * CC) + lane);
        a2.x += pj * v.x;
        a2.y += pj * v.y;
    }
    *((float2*)(out + (size_t)src * CC) + lane) = a2;
}

extern "C" void kernel_launch(void* const* d_in, const int* in_sizes, int n_in,
                              void* d_out, int out_size, void* d_ws, size_t ws_size,
                              hipStream_t stream)
{
    const float* wv   = (const float*)d_in[0];
    const int*   src  = (const int*)d_in[1];
    const int*   nei  = (const int*)d_in[2];
    const int*   msk  = (const int*)d_in[3];
    const float* W    = (const float*)d_in[4];
    const float* bias = (const float*)d_in[5];
    float* out = (float*)d_out;
    float* P   = (float*)d_ws;   // N*CC*4 = 51.2 MB scratch

    dim3 g1((NN + 63) / 64, 2);
    proj_kernel<<<g1, 256, 0, stream>>>(wv, W, bias, P, out);

    const int waves = SS;                       // one wave per s
    const int blocks = (waves * 64) / 256;      // 12500
    attn_kernel<<<blocks, 256, 0, stream>>>(wv, src, nei, msk, P, out);
}